// Round 2
// baseline (1058.386 us; speedup 1.0000x reference)
//
#include <hip/hip_runtime.h>

// ---------------------------------------------------------------------------
// Fused forward: conv1+pool+relu -> conv2+pool+relu -> lin + message passing
// + fc1/fc2/fc3.  All tensors are float32 (per the JAX reference).
//
// K1 (all the HBM traffic, ~771 MB input): one block per (image, pooled row).
// K2: one 64-thread block per image (16.4 KB LDS stage).
// K3: one block per node, everything in LDS.
// ---------------------------------------------------------------------------

#define K1_PITCH 228   // 224 + 4: rotates row base across banks

__global__ __launch_bounds__(128) void k1_conv1(const float* __restrict__ nodes,
                                                const float* __restrict__ w1,
                                                const float* __restrict__ b1,
                                                float* __restrict__ ws1)
{
    __shared__ float lds[21 * K1_PITCH];
    const int blk  = blockIdx.x;
    const int b    = blk / 37;
    const int py   = blk % 37;
    const int row0 = 6 * py;                      // input rows row0..row0+6 (<224)
    const int tid  = threadIdx.x;
    const float* img = nodes + (size_t)b * 150528;   // 3*224*224

    // stage 21 rows (3ch x 7rows) x 224 cols; float4 (16B) per load
    for (int idx = tid; idx < 1176; idx += 128) { // 1176 = 21*56
        const int r21 = idx / 56, ck = idx % 56;
        const int ch = r21 / 7, r = r21 % 7;
        const float4 v = *(const float4*)(img + ch * 50176 + (row0 + r) * 224 + ck * 4);
        float* d = &lds[r21 * K1_PITCH + ck * 4];
        d[0] = v.x; d[1] = v.y; d[2] = v.z; d[3] = v.w;
    }
    __syncthreads();

    if (tid < 111) {
        const int c  = tid / 37;        // output channel
        const int px = tid - 37 * c;    // pooled column
        float wv[27];                   // conv1_w[c][ci][kh][kw]
        #pragma unroll
        for (int t = 0; t < 27; t++) wv[t] = w1[c * 27 + t];
        const float bias = b1[c];

        // acc[j][i] = conv output at (conv row 3py+j, conv col 3px+i)
        float acc[3][3];
        #pragma unroll
        for (int j = 0; j < 3; j++)
            #pragma unroll
            for (int i = 0; i < 3; i++) acc[j][i] = bias;

        #pragma unroll
        for (int ci = 0; ci < 3; ci++) {
            const float* L = &lds[ci * 7 * K1_PITCH + 6 * px];
            #pragma unroll
            for (int r = 0; r < 7; r++) {       // local input row
                float row[7];
                #pragma unroll
                for (int k = 0; k < 7; k++) row[k] = L[r * K1_PITCH + k];
                #pragma unroll
                for (int j = 0; j < 3; j++) {
                    const int kh = r - 2 * j;   // conv row j uses local rows 2j..2j+2
                    if (kh >= 0 && kh < 3) {
                        #pragma unroll
                        for (int i = 0; i < 3; i++)
                            #pragma unroll
                            for (int kw = 0; kw < 3; kw++)
                                acc[j][i] += wv[(ci * 3 + kh) * 3 + kw] * row[2 * i + kw];
                    }
                }
            }
        }
        float m = acc[0][0];
        #pragma unroll
        for (int j = 0; j < 3; j++)
            #pragma unroll
            for (int i = 0; i < 3; i++) m = fmaxf(m, acc[j][i]);
        m = fmaxf(m, 0.0f);   // relu(maxpool) == maxpool(relu-free) then relu (monotone)
        ws1[((size_t)(b * 3 + c) * 37 + py) * 37 + px] = m;
    }
}

// ---------------------------------------------------------------------------
// K2: conv2 (3->1ch, 3x3, stride2) + maxpool3x3(s3) + relu
//   in : ws1 f32 [1280][3][37][37]   out: ws2 f32 [1280][36]
// ---------------------------------------------------------------------------
__global__ __launch_bounds__(64) void k2_conv2(const float* __restrict__ ws1,
                                               const float* __restrict__ w2,
                                               const float* __restrict__ b2,
                                               float* __restrict__ ws2)
{
    __shared__ float lds[3 * 37 * 37];   // 4107 floats
    const int b = blockIdx.x, tid = threadIdx.x;
    const float* src = ws1 + (size_t)b * 4107;
    for (int i = tid; i < 4107; i += 64) lds[i] = src[i];
    __syncthreads();

    if (tid < 36) {
        const int py = tid / 6, px = tid % 6;
        float wv[27];
        #pragma unroll
        for (int t = 0; t < 27; t++) wv[t] = w2[t];
        const float bias = b2[0];

        float acc[3][3];
        #pragma unroll
        for (int j = 0; j < 3; j++)
            #pragma unroll
            for (int i = 0; i < 3; i++) acc[j][i] = bias;

        #pragma unroll
        for (int ci = 0; ci < 3; ci++) {
            #pragma unroll
            for (int r = 0; r < 7; r++) {
                const float* L = &lds[ci * 1369 + (6 * py + r) * 37 + 6 * px];
                float row[7];
                #pragma unroll
                for (int k = 0; k < 7; k++) row[k] = L[k];
                #pragma unroll
                for (int j = 0; j < 3; j++) {
                    const int kh = r - 2 * j;
                    if (kh >= 0 && kh < 3) {
                        #pragma unroll
                        for (int i = 0; i < 3; i++)
                            #pragma unroll
                            for (int kw = 0; kw < 3; kw++)
                                acc[j][i] += wv[(ci * 3 + kh) * 3 + kw] * row[2 * i + kw];
                    }
                }
            }
        }
        float m = acc[0][0];
        #pragma unroll
        for (int j = 0; j < 3; j++)
            #pragma unroll
            for (int i = 0; i < 3; i++) m = fmaxf(m, acc[j][i]);
        ws2[b * 36 + tid] = fmaxf(m, 0.0f);
    }
}

// ---------------------------------------------------------------------------
// K3: lin + message passing (msg/agg/last) + fc1/fc2/fc3. One block per node.
// ---------------------------------------------------------------------------
__global__ __launch_bounds__(128) void k3_head(const float* __restrict__ ws2,
    const float* __restrict__ pos, const float* __restrict__ attmap,
    const float* __restrict__ lin_w, const float* __restrict__ lin_b,
    const float* __restrict__ frame_w, const float* __restrict__ frame_b,
    const float* __restrict__ last_w, const float* __restrict__ last_b,
    const float* __restrict__ fc1_w, const float* __restrict__ fc1_b,
    const float* __restrict__ fc2_w, const float* __restrict__ fc2_b,
    const float* __restrict__ fc3_w, const float* __restrict__ fc3_b,
    float* __restrict__ out)
{
    __shared__ float feat[240];   // [f*4+n][12]: [0:6)=nodes_feature, [6:12)=pos_updata
    __shared__ float msg[120];    // [f][n][d] -> f*24+n*6+d
    __shared__ float h1[120];
    __shared__ float h2[60];
    const int b = blockIdx.x, tid = threadIdx.x;

    if (tid < 120) {
        const int f = tid / 24, n = (tid / 6) % 4, d = tid % 6;
        // nodes_feature[f][n][d] = ws2[b,f,n,:] . lin_w[d,:] + lin_b[d]
        const float* xs = ws2 + (size_t)((b * 20) + f * 4 + n) * 36;
        float s = lin_b[d];
        #pragma unroll
        for (int k = 0; k < 36; k++) s += xs[k] * lin_w[d * 36 + k];
        feat[(f * 4 + n) * 12 + d] = s;
        // msg[f][n][d] = pos[b,f,n,:] . frame_w[d,:] + frame_b[d]
        float m = frame_b[d];
        #pragma unroll
        for (int k = 0; k < 6; k++)
            m += pos[(((b * 5 + f) * 4 + n) * 6) + k] * frame_w[d * 6 + k];
        msg[tid] = m;
    }
    __syncthreads();
    if (tid < 120) {
        const int f = tid / 24, n = (tid / 6) % 4, d = tid % 6;
        // agg[f][n][d] = sum_j attmap[b,f,j,n] * msg[f][j][d]
        float a = 0.0f;
        #pragma unroll
        for (int j = 0; j < 4; j++)
            a += attmap[((b * 5 + f) * 4 + j) * 4 + n] * msg[f * 24 + j * 6 + d];
        if (f > 0) {   // + last[f-1][n][d] = pos[b,f-1,n,:] . last_w[d,:] + last_b[d]
            float l = last_b[d];
            #pragma unroll
            for (int k = 0; k < 6; k++)
                l += pos[(((b * 5 + (f - 1)) * 4 + n) * 6) + k] * last_w[d * 6 + k];
            a += l;
        }
        feat[(f * 4 + n) * 12 + 6 + d] = a;
    }
    __syncthreads();
    if (tid < 120) {
        float s = fc1_b[tid];
        for (int k = 0; k < 240; k++) s += feat[k] * fc1_w[tid * 240 + k];
        h1[tid] = fmaxf(s, 0.0f);
    }
    __syncthreads();
    if (tid < 60) {
        float s = fc2_b[tid];
        for (int k = 0; k < 120; k++) s += h1[k] * fc2_w[tid * 120 + k];
        h2[tid] = fmaxf(s, 0.0f);
    }
    __syncthreads();
    if (tid < 6) {
        float s = fc3_b[tid];
        for (int k = 0; k < 60; k++) s += h2[k] * fc3_w[tid * 60 + k];
        out[b * 6 + tid] = s;
    }
}

extern "C" void kernel_launch(void* const* d_in, const int* in_sizes, int n_in,
                              void* d_out, int out_size, void* d_ws, size_t ws_size,
                              hipStream_t stream) {
    const float* nodes   = (const float*)d_in[0];
    const float* pos     = (const float*)d_in[1];
    const float* attmap  = (const float*)d_in[2];
    // d_in[3] = depths (unused by the forward pass)
    const float* conv1_w = (const float*)d_in[4];
    const float* conv1_b = (const float*)d_in[5];
    const float* conv2_w = (const float*)d_in[6];
    const float* conv2_b = (const float*)d_in[7];
    const float* lin_w   = (const float*)d_in[8];
    const float* lin_b   = (const float*)d_in[9];
    const float* frame_w = (const float*)d_in[10];
    const float* frame_b = (const float*)d_in[11];
    const float* last_w  = (const float*)d_in[12];
    const float* last_b  = (const float*)d_in[13];
    const float* fc1_w   = (const float*)d_in[14];
    const float* fc1_b   = (const float*)d_in[15];
    const float* fc2_w   = (const float*)d_in[16];
    const float* fc2_b   = (const float*)d_in[17];
    const float* fc3_w   = (const float*)d_in[18];
    const float* fc3_b   = (const float*)d_in[19];

    float* ws1 = (float*)d_ws;            // [1280*3*37*37] = 5,256,960 f32 (~21 MB)
    float* ws2 = ws1 + 5256960;           // [1280*36]      = 46,080 f32

    k1_conv1<<<1280 * 37, 128, 0, stream>>>(nodes, conv1_w, conv1_b, ws1);
    k2_conv2<<<1280, 64, 0, stream>>>(ws1, conv2_w, conv2_b, ws2);
    k3_head<<<64, 128, 0, stream>>>(ws2, pos, attmap, lin_w, lin_b, frame_w, frame_b,
                                    last_w, last_b, fc1_w, fc1_b, fc2_w, fc2_b,
                                    fc3_w, fc3_b, (float*)d_out);
}